// Round 1
// baseline (208.790 us; speedup 1.0000x reference)
//
#include <hip/hip_runtime.h>
#include <hip/hip_bf16.h>

#define BATCH 4
#define CDIM  64
#define CKD   8
#define NPOS  4096
#define ITILE 64
#define JTILE 64
#define VSTR  72   // LDS V-tile row stride in bf16 elements (64 + 8 pad, keeps 16B align)

typedef __bf16 bf16x8 __attribute__((ext_vector_type(8)));
typedef float  f32x4  __attribute__((ext_vector_type(4)));

// ---------------- projection: q,k (fp32) + v (bf16, c-major) ----------------
__global__ __launch_bounds__(256) void proj_kernel(
    const float* __restrict__ x,
    const float* __restrict__ wq, const float* __restrict__ bq,
    const float* __restrict__ wk, const float* __restrict__ bk,
    const float* __restrict__ wv, const float* __restrict__ bv,
    float* __restrict__ qf, float* __restrict__ kf,
    __hip_bfloat16* __restrict__ vbf)
{
    const int g    = blockIdx.x * 256 + threadIdx.x;   // 65536 threads
    const int part = g >> 14;                          // 0..3 (uniform per WG)
    const int pos  = g & 16383;
    const int b    = pos >> 12;
    const int n    = pos & 4095;

    const float* xb = x + (size_t)b * CDIM * NPOS + n;
    float xr[CDIM];
#pragma unroll
    for (int c = 0; c < CDIM; ++c) xr[c] = xb[(size_t)c * NPOS];

    if (part == 0) {
        float* qo = qf + ((size_t)(b * NPOS + n)) * CKD;
#pragma unroll
        for (int o = 0; o < CKD; ++o) {
            float a = bq[o];
            const float* w = wq + o * CDIM;
#pragma unroll
            for (int c = 0; c < CDIM; ++c) a = fmaf(w[c], xr[c], a);
            qo[o] = a;
        }
    } else if (part == 1) {
        float* ko = kf + ((size_t)(b * NPOS + n)) * CKD;
#pragma unroll
        for (int o = 0; o < CKD; ++o) {
            float a = bk[o];
            const float* w = wk + o * CDIM;
#pragma unroll
            for (int c = 0; c < CDIM; ++c) a = fmaf(w[c], xr[c], a);
            ko[o] = a;
        }
    }
    // v channels [16*part, 16*part+16)
    const int c0 = part * 16;
#pragma unroll
    for (int o = 0; o < 16; ++o) {
        const int oc = c0 + o;
        float a = bv[oc];
        const float* w = wv + oc * CDIM;
#pragma unroll
        for (int c = 0; c < CDIM; ++c) a = fmaf(w[c], xr[c], a);
        vbf[((size_t)b * CDIM + oc) * NPOS + n] = __float2bfloat16(a);
    }
}

// ---------------- flash attention, bf16-MFMA PV, fp32 softmax ----------------
__global__ __launch_bounds__(256) void attn_kernel(
    const float* __restrict__ x,
    const float* __restrict__ qf, const float* __restrict__ kf,
    const __hip_bfloat16* __restrict__ vbf,
    const float* __restrict__ gamma,
    float* __restrict__ out)
{
    __shared__ __hip_bfloat16 vt[CDIM][VSTR];  // V^T tile: [c][j], j contiguous
    __shared__ float kt[JTILE][CKD];           // K tile: [j][8]

    const int b     = blockIdx.x >> 6;
    const int itile = blockIdx.x & 63;
    const int tid   = threadIdx.x;
    const int wave  = tid >> 6;
    const int lane  = tid & 63;
    const int quad  = lane >> 4;
    const int m16   = lane & 15;

    const int i0   = itile * ITILE + wave * 16;  // my wave's query strip base
    const int qrow = i0 + m16;

    // per-lane query vector (A-frag row = lane&15)
    const float* qp = qf + ((size_t)(b * NPOS + qrow)) * CKD;
    const float4 q0 = *(const float4*)qp;
    const float4 q1 = *(const float4*)(qp + 4);

    f32x4 acc[4];
#pragma unroll
    for (int nb = 0; nb < 4; ++nb) acc[nb] = (f32x4){0.f, 0.f, 0.f, 0.f};
    float m_run = -1e30f;
    float l_run = 0.f;

    const __hip_bfloat16* vbase = vbf + (size_t)b * CDIM * NPOS;
    const float*          kbase = kf  + (size_t)b * NPOS * CKD;

    // staging indices (V: 4 threads per c-row, 32B each)
    const int sc  = tid >> 2;
    const int seg = tid & 3;

    for (int jt = 0; jt < NPOS; jt += JTILE) {
        // ---- stage V tile (c-major, contiguous j) ----
        {
            const uint4* src = (const uint4*)(vbase + (size_t)sc * NPOS + jt + seg * 16);
            uint4 v0 = src[0];
            uint4 v1 = src[1];
            *(uint4*)&vt[sc][seg * 16]     = v0;
            *(uint4*)&vt[sc][seg * 16 + 8] = v1;
        }
        // ---- stage K tile (contiguous 2 KB) ----
        {
            const float2* src = (const float2*)(kbase + (size_t)jt * CKD);
            ((float2*)kt)[tid] = src[tid];
        }
        __syncthreads();

        // ---- S strip in A-frag layout: row=m16, j = kb*32 + quad*8 + u ----
        float p[2][8];
        float tmax = -1e30f;
#pragma unroll
        for (int kb = 0; kb < 2; ++kb) {
#pragma unroll
            for (int u = 0; u < 8; ++u) {
                const int jl = kb * 32 + quad * 8 + u;
                const float4 k0 = *(const float4*)&kt[jl][0];
                const float4 k1 = *(const float4*)&kt[jl][4];
                float s = q0.x * k0.x;
                s = fmaf(q0.y, k0.y, s);
                s = fmaf(q0.z, k0.z, s);
                s = fmaf(q0.w, k0.w, s);
                s = fmaf(q1.x, k1.x, s);
                s = fmaf(q1.y, k1.y, s);
                s = fmaf(q1.z, k1.z, s);
                s = fmaf(q1.w, k1.w, s);
                p[kb][u] = s;
                tmax = fmaxf(tmax, s);
            }
        }
        // row max across quads (lanes m16, m16+16, m16+32, m16+48)
        tmax = fmaxf(tmax, __shfl_xor(tmax, 16));
        tmax = fmaxf(tmax, __shfl_xor(tmax, 32));

        const float m_new = fmaxf(m_run, tmax);
        const float alpha = __expf(m_run - m_new);

        float psum = 0.f;
#pragma unroll
        for (int kb = 0; kb < 2; ++kb)
#pragma unroll
            for (int u = 0; u < 8; ++u) {
                const float e = __expf(p[kb][u] - m_new);
                p[kb][u] = e;
                psum += e;
            }
        psum += __shfl_xor(psum, 16);
        psum += __shfl_xor(psum, 32);
        l_run = l_run * alpha + psum;
        m_run = m_new;

        // pack P to bf16 A-frags
        bf16x8 afrag[2];
#pragma unroll
        for (int kb = 0; kb < 2; ++kb)
#pragma unroll
            for (int u = 0; u < 8; ++u)
                afrag[kb][u] = (__bf16)p[kb][u];

        // rescale accumulators: acc rows are local rows quad*4+r, alpha lives at lane==row
        float al[4];
#pragma unroll
        for (int r = 0; r < 4; ++r) al[r] = __shfl(alpha, quad * 4 + r);
#pragma unroll
        for (int nb = 0; nb < 4; ++nb)
#pragma unroll
            for (int r = 0; r < 4; ++r) acc[nb][r] *= al[r];

        // ---- PV MFMA: O[16 x 64] += P[16 x 64] * Vt[64 x 64] ----
#pragma unroll
        for (int nb = 0; nb < 4; ++nb) {
            const int c = nb * 16 + m16;
            const bf16x8 b0 = *(const bf16x8*)&vt[c][quad * 8];
            const bf16x8 b1 = *(const bf16x8*)&vt[c][32 + quad * 8];
            acc[nb] = __builtin_amdgcn_mfma_f32_16x16x32_bf16(afrag[0], b0, acc[nb], 0, 0, 0);
            acc[nb] = __builtin_amdgcn_mfma_f32_16x16x32_bf16(afrag[1], b1, acc[nb], 0, 0, 0);
        }
        __syncthreads();
    }

    // ---- epilogue: normalize, gamma*O + x ----
    const float linv = 1.f / l_run;
    float lr[4];
#pragma unroll
    for (int r = 0; r < 4; ++r) lr[r] = __shfl(linv, quad * 4 + r);
    const float g0 = gamma[0];

#pragma unroll
    for (int nb = 0; nb < 4; ++nb) {
        const int c = nb * 16 + m16;
#pragma unroll
        for (int r = 0; r < 4; ++r) {
            const int i = i0 + quad * 4 + r;
            const size_t idx = ((size_t)(b * CDIM + c)) * NPOS + i;
            out[idx] = fmaf(g0, acc[nb][r] * lr[r], x[idx]);
        }
    }
}

// ---------------- launch ----------------
extern "C" void kernel_launch(void* const* d_in, const int* in_sizes, int n_in,
                              void* d_out, int out_size, void* d_ws, size_t ws_size,
                              hipStream_t stream)
{
    const float* x     = (const float*)d_in[0];
    const float* wq    = (const float*)d_in[1];
    const float* bq    = (const float*)d_in[2];
    const float* wk    = (const float*)d_in[3];
    const float* bk    = (const float*)d_in[4];
    const float* wv    = (const float*)d_in[5];
    const float* bv    = (const float*)d_in[6];
    const float* gamma = (const float*)d_in[7];
    float* out = (float*)d_out;

    char* ws = (char*)d_ws;
    float*          qf  = (float*)ws;                      // 4*4096*8*4  = 512 KB
    float*          kf  = (float*)(ws + (512 << 10));      // 512 KB
    __hip_bfloat16* vbf = (__hip_bfloat16*)(ws + (1 << 20)); // 4*64*4096*2 = 2 MB

    proj_kernel<<<256, 256, 0, stream>>>(x, wq, bq, wk, bk, wv, bv, qf, kf, vbf);
    attn_kernel<<<BATCH * (NPOS / ITILE), 256, 0, stream>>>(x, qf, kf, vbf, gamma, out);
}

// Round 2
// 169.834 us; speedup vs baseline: 1.2294x; 1.2294x over previous
//
#include <hip/hip_runtime.h>
#include <hip/hip_bf16.h>

#define BATCH  4
#define CDIM   64
#define CKD    8
#define NPOS   4096
#define SPLIT  4
#define JCHUNK (NPOS / SPLIT)    // 1024
#define JTILE  64
#define NITER  (JCHUNK / JTILE)  // 16
#define PTP    72                // LDS P-tile col stride (elements): 144 B, 16B-aligned, bank-balanced

typedef _Float16 f16x8 __attribute__((ext_vector_type(8)));
typedef float    f32x4 __attribute__((ext_vector_type(4)));

// ---------------- projection: q,k,v -> fp16 (streamed x, no big per-thread array) ----------------
__global__ __launch_bounds__(256) void proj_kernel(
    const float* __restrict__ x,
    const float* __restrict__ wq, const float* __restrict__ bq,
    const float* __restrict__ wk, const float* __restrict__ bk,
    const float* __restrict__ wv, const float* __restrict__ bv,
    _Float16* __restrict__ qh, _Float16* __restrict__ kh,
    _Float16* __restrict__ vh)
{
    const int g    = blockIdx.x * 256 + threadIdx.x;   // 65536 threads
    const int part = g >> 14;                          // 0..3, uniform per WG
    const int pos  = g & 16383;
    const int b    = pos >> 12;
    const int n    = pos & 4095;
    const int c0   = part * 16;

    const float* xb = x + (size_t)b * CDIM * NPOS + n;

    float vacc[16];
#pragma unroll
    for (int o = 0; o < 16; ++o) vacc[o] = 0.f;

    if (part < 2) {  // uniform branch: q-or-k (8) + v slice (16)
        const float* wqk = (part == 0) ? wq : wk;
        const float* bqk = (part == 0) ? bq : bk;
        float qacc[8];
#pragma unroll
        for (int o = 0; o < 8; ++o) qacc[o] = 0.f;
#pragma unroll 4
        for (int c = 0; c < CDIM; ++c) {
            const float xv = xb[(size_t)c * NPOS];
#pragma unroll
            for (int o = 0; o < 8; ++o)  qacc[o] = fmaf(wqk[o * CDIM + c], xv, qacc[o]);
#pragma unroll
            for (int o = 0; o < 16; ++o) vacc[o] = fmaf(wv[(c0 + o) * CDIM + c], xv, vacc[o]);
        }
        f16x8 qv;
#pragma unroll
        for (int o = 0; o < 8; ++o) qv[o] = (_Float16)(qacc[o] + bqk[o]);
        _Float16* dst = ((part == 0) ? qh : kh) + ((size_t)(b * NPOS + n)) * CKD;
        *(f16x8*)dst = qv;
    } else {         // v slice only
#pragma unroll 4
        for (int c = 0; c < CDIM; ++c) {
            const float xv = xb[(size_t)c * NPOS];
#pragma unroll
            for (int o = 0; o < 16; ++o) vacc[o] = fmaf(wv[(c0 + o) * CDIM + c], xv, vacc[o]);
        }
    }
#pragma unroll
    for (int o = 0; o < 16; ++o)
        vh[((size_t)(b * CDIM + c0 + o)) * NPOS + n] = (_Float16)(vacc[o] + bv[c0 + o]);
}

// ---------------- flash attention: MFMA-S + MFMA-PV, barrier-free, split-j ----------------
__global__ __launch_bounds__(256, 4) void attn_kernel(
    const _Float16* __restrict__ qh, const _Float16* __restrict__ kh,
    const _Float16* __restrict__ vh,
    _Float16* __restrict__ po, float* __restrict__ pm, float* __restrict__ pl)
{
    __shared__ _Float16 pt[4][16][PTP];   // per-wave private P-transform tile

    const int bid   = blockIdx.x;
    const int split = bid & (SPLIT - 1);
    const int itile = (bid >> 2) & 63;
    const int b     = bid >> 8;
    const int tid   = threadIdx.x;
    const int wave  = tid >> 6;
    const int lane  = tid & 63;
    const int quad  = lane >> 4;
    const int m16   = lane & 15;

    const int i0 = itile * 64 + wave * 16;

    // Q A-fragment: A[m=m16][k=quad*8+u]; k>=8 is zero padding -> quads 1..3 hold zeros
    f16x8 qa = {};
    if (quad == 0)
        qa = *(const f16x8*)(qh + ((size_t)(b * NPOS + i0 + m16)) * CKD);

    f32x4 acc[4];
#pragma unroll
    for (int nb = 0; nb < 4; ++nb) acc[nb] = (f32x4){0.f, 0.f, 0.f, 0.f};
    float m_run[4], l_run[4];
#pragma unroll
    for (int r = 0; r < 4; ++r) { m_run[r] = -1e30f; l_run[r] = 0.f; }

    const _Float16* kbase = kh + (size_t)b * NPOS * CKD;
    const _Float16* vbase = vh + (size_t)b * CDIM * NPOS;

    for (int it = 0; it < NITER; ++it) {
        const int j0 = split * JCHUNK + it * JTILE;

        // ---- S = Q K^T via MFMA (4 independent 16x16 j-blocks) ----
        f32x4 sf[4];
#pragma unroll
        for (int jb = 0; jb < 4; ++jb) {
            // B[k=quad*8+u][n=n16] = K[j0+jb*16+n16][u], zeros for k>=8
            f16x8 kf = {};
            if (quad == 0)
                kf = *(const f16x8*)(kbase + ((size_t)(j0 + jb * 16 + m16)) * CKD);
            sf[jb] = __builtin_amdgcn_mfma_f32_16x16x32_f16(qa, kf, (f32x4){0.f,0.f,0.f,0.f}, 0, 0, 0);
        }

        // ---- online softmax; lane holds rows i_local = quad*4+r, cols jb*16+m16 ----
        float mx[4];
#pragma unroll
        for (int r = 0; r < 4; ++r)
            mx[r] = fmaxf(fmaxf(sf[0][r], sf[1][r]), fmaxf(sf[2][r], sf[3][r]));
#pragma unroll
        for (int d = 1; d < 16; d <<= 1)
#pragma unroll
            for (int r = 0; r < 4; ++r)
                mx[r] = fmaxf(mx[r], __shfl_xor(mx[r], d));

        float alpha[4], ps[4];
#pragma unroll
        for (int r = 0; r < 4; ++r) {
            const float mnew = fmaxf(m_run[r], mx[r]);
            alpha[r] = __expf(m_run[r] - mnew);
            m_run[r] = mnew;
            ps[r]    = 0.f;
        }
        float pf[4][4];
#pragma unroll
        for (int jb = 0; jb < 4; ++jb)
#pragma unroll
            for (int r = 0; r < 4; ++r) {
                const float e = __expf(sf[jb][r] - m_run[r]);
                pf[jb][r] = e;
                ps[r] += e;
            }
#pragma unroll
        for (int d = 1; d < 16; d <<= 1)
#pragma unroll
            for (int r = 0; r < 4; ++r)
                ps[r] += __shfl_xor(ps[r], d);
#pragma unroll
        for (int r = 0; r < 4; ++r)
            l_run[r] = l_run[r] * alpha[r] + ps[r];
#pragma unroll
        for (int nb = 0; nb < 4; ++nb)
#pragma unroll
            for (int r = 0; r < 4; ++r)
                acc[nb][r] *= alpha[r];

        // ---- P: C-layout -> A-layout via wave-private LDS (no barrier) ----
#pragma unroll
        for (int jb = 0; jb < 4; ++jb)
#pragma unroll
            for (int r = 0; r < 4; ++r)
                pt[wave][quad * 4 + r][jb * 16 + m16] = (_Float16)pf[jb][r];

        const f16x8 pa0 = *(const f16x8*)&pt[wave][m16][quad * 8];
        const f16x8 pa1 = *(const f16x8*)&pt[wave][m16][32 + quad * 8];

        // ---- PV: O[16x64] += P[16x64] * V[64x64], V B-frags straight from global ----
#pragma unroll
        for (int nb = 0; nb < 4; ++nb) {
            const _Float16* vp = vbase + ((size_t)(nb * 16 + m16)) * NPOS + j0 + quad * 8;
            const f16x8 v0 = *(const f16x8*)vp;
            const f16x8 v1 = *(const f16x8*)(vp + 32);
            acc[nb] = __builtin_amdgcn_mfma_f32_16x16x32_f16(pa0, v0, acc[nb], 0, 0, 0);
            acc[nb] = __builtin_amdgcn_mfma_f32_16x16x32_f16(pa1, v1, acc[nb], 0, 0, 0);
        }
    }

    // ---- epilogue: store unnormalized partial O (f16) + m,l (f32) ----
    const int sb = split * BATCH + b;
    if (m16 == 0) {
#pragma unroll
        for (int r = 0; r < 4; ++r) {
            const int i = i0 + quad * 4 + r;
            pm[(size_t)sb * NPOS + i] = m_run[r];
            pl[(size_t)sb * NPOS + i] = l_run[r];
        }
    }
    // transpose acc through pt for coalesced po stores
#pragma unroll
    for (int nb = 0; nb < 4; ++nb)
#pragma unroll
        for (int r = 0; r < 4; ++r)
            pt[wave][quad * 4 + r][nb * 16 + m16] = (_Float16)acc[nb][r];
#pragma unroll
    for (int g = 0; g < 16; ++g) {
        const int c = quad + g * 4;
        po[((size_t)sb * CDIM + c) * NPOS + i0 + m16] = pt[wave][m16][c];
    }
}

// ---------------- combine split-j partials + gamma*O + x ----------------
__global__ __launch_bounds__(256) void combine_kernel(
    const float* __restrict__ x,
    const _Float16* __restrict__ po, const float* __restrict__ pm,
    const float* __restrict__ pl,
    const float* __restrict__ gamma, float* __restrict__ out)
{
    const int t = blockIdx.x * 256 + threadIdx.x;   // 1,048,576 threads
    const int b = t >> 18;
    const int c = (t >> 12) & 63;
    const int i = t & 4095;

    float m[SPLIT], l[SPLIT];
#pragma unroll
    for (int s = 0; s < SPLIT; ++s) {
        m[s] = pm[((size_t)(s * BATCH + b)) * NPOS + i];
        l[s] = pl[((size_t)(s * BATCH + b)) * NPOS + i];
    }
    float ms = m[0];
#pragma unroll
    for (int s = 1; s < SPLIT; ++s) ms = fmaxf(ms, m[s]);

    float L = 0.f, O = 0.f;
#pragma unroll
    for (int s = 0; s < SPLIT; ++s) {
        const float w = __expf(m[s] - ms);
        L += l[s] * w;
        O = fmaf(w, (float)po[(((size_t)(s * BATCH + b)) * CDIM + c) * NPOS + i], O);
    }
    const size_t xi = ((size_t)(b * CDIM + c)) * NPOS + i;
    out[xi] = fmaf(gamma[0], O / L, x[xi]);
}

// ---------------- launch ----------------
extern "C" void kernel_launch(void* const* d_in, const int* in_sizes, int n_in,
                              void* d_out, int out_size, void* d_ws, size_t ws_size,
                              hipStream_t stream)
{
    const float* x     = (const float*)d_in[0];
    const float* wq    = (const float*)d_in[1];
    const float* bq    = (const float*)d_in[2];
    const float* wk    = (const float*)d_in[3];
    const float* bk    = (const float*)d_in[4];
    const float* wv    = (const float*)d_in[5];
    const float* bv    = (const float*)d_in[6];
    const float* gamma = (const float*)d_in[7];
    float* out = (float*)d_out;

    char* ws = (char*)d_ws;
    _Float16* qh = (_Float16*)(ws);                      // 4*4096*8*2   = 256 KB
    _Float16* kh = (_Float16*)(ws + (256 << 10));        // 256 KB
    _Float16* vh = (_Float16*)(ws + (512 << 10));        // 4*64*4096*2  = 2 MB
    _Float16* po = (_Float16*)(ws + ((512 + 2048) << 10));           // SPLIT*4*64*4096*2 = 8 MB
    float*    pm = (float*)   (ws + ((512 + 2048 + 8192) << 10));    // 256 KB
    float*    pl = (float*)   (ws + ((512 + 2048 + 8192 + 256) << 10)); // 256 KB

    proj_kernel<<<256, 256, 0, stream>>>(x, wq, bq, wk, bk, wv, bv, qh, kh, vh);
    attn_kernel<<<BATCH * 64 * SPLIT, 256, 0, stream>>>(qh, kh, vh, po, pm, pl);
    combine_kernel<<<4096, 256, 0, stream>>>(x, po, pm, pl, gamma, out);
}

// Round 3
// 168.496 us; speedup vs baseline: 1.2391x; 1.0079x over previous
//
#include <hip/hip_runtime.h>
#include <hip/hip_bf16.h>

#define BATCH  4
#define CDIM   64
#define CKD    8
#define NPOS   4096
#define SPLIT  4
#define JCHUNK (NPOS / SPLIT)    // 1024
#define NITER  (JCHUNK / 64)     // 16
#define PTP    72                // LDS P-tile col stride (elements)

typedef _Float16 f16x8 __attribute__((ext_vector_type(8)));
typedef float    f32x4 __attribute__((ext_vector_type(4)));

// ---------------- projection: q,k,v -> fp16 ----------------
__global__ __launch_bounds__(256) void proj_kernel(
    const float* __restrict__ x,
    const float* __restrict__ wq, const float* __restrict__ bq,
    const float* __restrict__ wk, const float* __restrict__ bk,
    const float* __restrict__ wv, const float* __restrict__ bv,
    _Float16* __restrict__ qh, _Float16* __restrict__ kh,
    _Float16* __restrict__ vh)
{
    const int g    = blockIdx.x * 256 + threadIdx.x;   // 65536 threads
    const int part = g >> 14;                          // 0..3, uniform per WG
    const int pos  = g & 16383;
    const int b    = pos >> 12;
    const int n    = pos & 4095;
    const int c0   = part * 16;

    const float* xb = x + (size_t)b * CDIM * NPOS + n;

    float vacc[16];
#pragma unroll
    for (int o = 0; o < 16; ++o) vacc[o] = 0.f;

    if (part < 2) {
        const float* wqk = (part == 0) ? wq : wk;
        const float* bqk = (part == 0) ? bq : bk;
        float qacc[8];
#pragma unroll
        for (int o = 0; o < 8; ++o) qacc[o] = 0.f;
#pragma unroll 4
        for (int c = 0; c < CDIM; ++c) {
            const float xv = xb[(size_t)c * NPOS];
#pragma unroll
            for (int o = 0; o < 8; ++o)  qacc[o] = fmaf(wqk[o * CDIM + c], xv, qacc[o]);
#pragma unroll
            for (int o = 0; o < 16; ++o) vacc[o] = fmaf(wv[(c0 + o) * CDIM + c], xv, vacc[o]);
        }
        f16x8 qv;
#pragma unroll
        for (int o = 0; o < 8; ++o) qv[o] = (_Float16)(qacc[o] + bqk[o]);
        _Float16* dst = ((part == 0) ? qh : kh) + ((size_t)(b * NPOS + n)) * CKD;
        *(f16x8*)dst = qv;
    } else {
#pragma unroll 4
        for (int c = 0; c < CDIM; ++c) {
            const float xv = xb[(size_t)c * NPOS];
#pragma unroll
            for (int o = 0; o < 16; ++o) vacc[o] = fmaf(wv[(c0 + o) * CDIM + c], xv, vacc[o]);
        }
    }
#pragma unroll
    for (int o = 0; o < 16; ++o)
        vh[((size_t)(b * CDIM + c0 + o)) * NPOS + n] = (_Float16)(vacc[o] + bv[c0 + o]);
}

// ---------------- flash attention: two-pass, shuffle-free inner loops ----------------
__global__ __launch_bounds__(256, 4) void attn_kernel(
    const _Float16* __restrict__ qh, const _Float16* __restrict__ kh,
    const _Float16* __restrict__ vh,
    _Float16* __restrict__ po, float* __restrict__ pm, float* __restrict__ pl)
{
    __shared__ _Float16 pt[4][16][PTP];   // per-wave private P-transform tile

    const int bid   = blockIdx.x;
    const int split = bid & (SPLIT - 1);
    const int itile = (bid >> 2) & 63;
    const int b     = bid >> 8;
    const int tid   = threadIdx.x;
    const int wave  = tid >> 6;
    const int lane  = tid & 63;
    const int quad  = lane >> 4;
    const int m16   = lane & 15;

    const int i0 = itile * 64 + wave * 16;

    // Q A-fragment: A[m=m16][k=quad*8+u]; zero k>=8 (quads 1..3)
    f16x8 qa = *(const f16x8*)(qh + ((size_t)(b * NPOS + i0 + m16)) * CKD);
    if (quad != 0) qa = (f16x8){};

    const _Float16* kchunk = kh + ((size_t)(b * NPOS + split * JCHUNK)) * CKD;
    const _Float16* vchunk = vh + (size_t)b * CDIM * NPOS + split * JCHUNK;

    // ---- pass 1: chunk row max (no per-iter cross-lane ops) ----
    float mloc[4];
#pragma unroll
    for (int r = 0; r < 4; ++r) mloc[r] = -1e30f;

    for (int it = 0; it < NITER; ++it) {
        const int j0 = it * 64;
        f16x8 kf[4];
#pragma unroll
        for (int jb = 0; jb < 4; ++jb)
            kf[jb] = *(const f16x8*)(kchunk + (size_t)(j0 + jb * 16 + m16) * CKD);
#pragma unroll
        for (int jb = 0; jb < 4; ++jb) {
            const f32x4 s = __builtin_amdgcn_mfma_f32_16x16x32_f16(
                qa, kf[jb], (f32x4){0.f, 0.f, 0.f, 0.f}, 0, 0, 0);
#pragma unroll
            for (int r = 0; r < 4; ++r) mloc[r] = fmaxf(mloc[r], s[r]);
        }
    }
    // single cross-lane reduce over the 16 col-lanes (rows live at quad*4+r)
#pragma unroll
    for (int d = 1; d < 16; d <<= 1)
#pragma unroll
        for (int r = 0; r < 4; ++r)
            mloc[r] = fmaxf(mloc[r], __shfl_xor(mloc[r], d));

    // ---- pass 2: exp -> P -> PV MFMA; l via ones-column MFMA ----
    f32x4 acc[4], accl;
#pragma unroll
    for (int nb = 0; nb < 4; ++nb) acc[nb] = (f32x4){0.f, 0.f, 0.f, 0.f};
    accl = (f32x4){0.f, 0.f, 0.f, 0.f};
    const f16x8 vones = {(_Float16)1.f, (_Float16)1.f, (_Float16)1.f, (_Float16)1.f,
                         (_Float16)1.f, (_Float16)1.f, (_Float16)1.f, (_Float16)1.f};

    for (int it = 0; it < NITER; ++it) {
        const int j0 = it * 64;

        // V B-frags straight from global (issue early, consumed last)
        f16x8 va[4], vb[4];
#pragma unroll
        for (int nb = 0; nb < 4; ++nb) {
            const _Float16* vp = vchunk + (size_t)(nb * 16 + m16) * NPOS + j0 + quad * 8;
            va[nb] = *(const f16x8*)vp;
            vb[nb] = *(const f16x8*)(vp + 32);
        }

        // S = Q K^T
        f32x4 sf[4];
#pragma unroll
        for (int jb = 0; jb < 4; ++jb) {
            const f16x8 kf = *(const f16x8*)(kchunk + (size_t)(j0 + jb * 16 + m16) * CKD);
            sf[jb] = __builtin_amdgcn_mfma_f32_16x16x32_f16(
                qa, kf, (f32x4){0.f, 0.f, 0.f, 0.f}, 0, 0, 0);
        }

        // P = exp(S - m), straight to LDS in A-layout (m is lane-local!)
#pragma unroll
        for (int jb = 0; jb < 4; ++jb)
#pragma unroll
            for (int r = 0; r < 4; ++r)
                pt[wave][quad * 4 + r][jb * 16 + m16] = (_Float16)__expf(sf[jb][r] - mloc[r]);

        const f16x8 pa0 = *(const f16x8*)&pt[wave][m16][quad * 8];
        const f16x8 pa1 = *(const f16x8*)&pt[wave][m16][32 + quad * 8];

        accl = __builtin_amdgcn_mfma_f32_16x16x32_f16(pa0, vones, accl, 0, 0, 0);
#pragma unroll
        for (int nb = 0; nb < 4; ++nb)
            acc[nb] = __builtin_amdgcn_mfma_f32_16x16x32_f16(pa0, va[nb], acc[nb], 0, 0, 0);
        accl = __builtin_amdgcn_mfma_f32_16x16x32_f16(pa1, vones, accl, 0, 0, 0);
#pragma unroll
        for (int nb = 0; nb < 4; ++nb)
            acc[nb] = __builtin_amdgcn_mfma_f32_16x16x32_f16(pa1, vb[nb], acc[nb], 0, 0, 0);
    }

    // ---- epilogue ----
    const int sb = split * BATCH + b;
    if (m16 == 0) {
#pragma unroll
        for (int r = 0; r < 4; ++r) {
            const int i = i0 + quad * 4 + r;
            pm[(size_t)sb * NPOS + i] = mloc[r];
            pl[(size_t)sb * NPOS + i] = accl[r];   // row-sum replicated across cols
        }
    }
    // transpose acc through pt for coalesced po stores (wave-private, in-order DS)
#pragma unroll
    for (int nb = 0; nb < 4; ++nb)
#pragma unroll
        for (int r = 0; r < 4; ++r)
            pt[wave][quad * 4 + r][nb * 16 + m16] = (_Float16)acc[nb][r];
#pragma unroll
    for (int g = 0; g < 16; ++g) {
        const int c = quad + g * 4;
        po[((size_t)sb * CDIM + c) * NPOS + i0 + m16] = pt[wave][m16][c];
    }
}

// ---------------- combine split-j partials + gamma*O + x ----------------
__global__ __launch_bounds__(256) void combine_kernel(
    const float* __restrict__ x,
    const _Float16* __restrict__ po, const float* __restrict__ pm,
    const float* __restrict__ pl,
    const float* __restrict__ gamma, float* __restrict__ out)
{
    const int t = blockIdx.x * 256 + threadIdx.x;   // 1,048,576 threads
    const int b = t >> 18;
    const int c = (t >> 12) & 63;
    const int i = t & 4095;

    float m[SPLIT], l[SPLIT];
#pragma unroll
    for (int s = 0; s < SPLIT; ++s) {
        m[s] = pm[((size_t)(s * BATCH + b)) * NPOS + i];
        l[s] = pl[((size_t)(s * BATCH + b)) * NPOS + i];
    }
    float ms = m[0];
#pragma unroll
    for (int s = 1; s < SPLIT; ++s) ms = fmaxf(ms, m[s]);

    float L = 0.f, O = 0.f;
#pragma unroll
    for (int s = 0; s < SPLIT; ++s) {
        const float w = __expf(m[s] - ms);
        L += l[s] * w;
        O = fmaf(w, (float)po[(((size_t)(s * BATCH + b)) * CDIM + c) * NPOS + i], O);
    }
    const size_t xi = ((size_t)(b * CDIM + c)) * NPOS + i;
    out[xi] = fmaf(gamma[0], O / L, x[xi]);
}

// ---------------- launch ----------------
extern "C" void kernel_launch(void* const* d_in, const int* in_sizes, int n_in,
                              void* d_out, int out_size, void* d_ws, size_t ws_size,
                              hipStream_t stream)
{
    const float* x     = (const float*)d_in[0];
    const float* wq    = (const float*)d_in[1];
    const float* bq    = (const float*)d_in[2];
    const float* wk    = (const float*)d_in[3];
    const float* bk    = (const float*)d_in[4];
    const float* wv    = (const float*)d_in[5];
    const float* bv    = (const float*)d_in[6];
    const float* gamma = (const float*)d_in[7];
    float* out = (float*)d_out;

    char* ws = (char*)d_ws;
    _Float16* qh = (_Float16*)(ws);                      // 256 KB
    _Float16* kh = (_Float16*)(ws + (256 << 10));        // 256 KB
    _Float16* vh = (_Float16*)(ws + (512 << 10));        // 2 MB
    _Float16* po = (_Float16*)(ws + ((512 + 2048) << 10));              // 8 MB
    float*    pm = (float*)   (ws + ((512 + 2048 + 8192) << 10));       // 256 KB
    float*    pl = (float*)   (ws + ((512 + 2048 + 8192 + 256) << 10)); // 256 KB

    proj_kernel<<<256, 256, 0, stream>>>(x, wq, bq, wk, bk, wv, bv, qh, kh, vh);
    attn_kernel<<<BATCH * 64 * SPLIT, 256, 0, stream>>>(qh, kh, vh, po, pm, pl);
    combine_kernel<<<4096, 256, 0, stream>>>(x, po, pm, pl, gamma, out);
}

// Round 4
// 144.251 us; speedup vs baseline: 1.4474x; 1.1681x over previous
//
#include <hip/hip_runtime.h>
#include <hip/hip_bf16.h>

#define BATCH  4
#define CDIM   64
#define CKD    8
#define NPOS   4096
#define SPLIT  4
#define JCHUNK (NPOS / SPLIT)    // 1024
#define NITER  (JCHUNK / 64)     // 16
#define PTP    72                // LDS P-tile col stride (elements)
#define VTP    72                // repack LDS row stride (elements)

typedef _Float16 f16x8 __attribute__((ext_vector_type(8)));
typedef float    f32x4 __attribute__((ext_vector_type(4)));

// ---------------- projection: q,k,v -> fp16 ----------------
__global__ __launch_bounds__(256) void proj_kernel(
    const float* __restrict__ x,
    const float* __restrict__ wq, const float* __restrict__ bq,
    const float* __restrict__ wk, const float* __restrict__ bk,
    const float* __restrict__ wv, const float* __restrict__ bv,
    _Float16* __restrict__ qh, _Float16* __restrict__ kh,
    _Float16* __restrict__ vh)
{
    const int g    = blockIdx.x * 256 + threadIdx.x;   // 65536 threads
    const int part = g >> 14;                          // 0..3, uniform per WG
    const int pos  = g & 16383;
    const int b    = pos >> 12;
    const int n    = pos & 4095;
    const int c0   = part * 16;

    const float* xb = x + (size_t)b * CDIM * NPOS + n;

    float vacc[16];
#pragma unroll
    for (int o = 0; o < 16; ++o) vacc[o] = 0.f;

    if (part < 2) {
        const float* wqk = (part == 0) ? wq : wk;
        const float* bqk = (part == 0) ? bq : bk;
        float qacc[8];
#pragma unroll
        for (int o = 0; o < 8; ++o) qacc[o] = 0.f;
#pragma unroll 4
        for (int c = 0; c < CDIM; ++c) {
            const float xv = xb[(size_t)c * NPOS];
#pragma unroll
            for (int o = 0; o < 8; ++o)  qacc[o] = fmaf(wqk[o * CDIM + c], xv, qacc[o]);
#pragma unroll
            for (int o = 0; o < 16; ++o) vacc[o] = fmaf(wv[(c0 + o) * CDIM + c], xv, vacc[o]);
        }
        f16x8 qv;
#pragma unroll
        for (int o = 0; o < 8; ++o) qv[o] = (_Float16)(qacc[o] + bqk[o]);
        _Float16* dst = ((part == 0) ? qh : kh) + ((size_t)(b * NPOS + n)) * CKD;
        *(f16x8*)dst = qv;
    } else {
#pragma unroll 4
        for (int c = 0; c < CDIM; ++c) {
            const float xv = xb[(size_t)c * NPOS];
#pragma unroll
            for (int o = 0; o < 16; ++o) vacc[o] = fmaf(wv[(c0 + o) * CDIM + c], xv, vacc[o]);
        }
    }
#pragma unroll
    for (int o = 0; o < 16; ++o)
        vh[((size_t)(b * CDIM + c0 + o)) * NPOS + n] = (_Float16)(vacc[o] + bv[c0 + o]);
}

// ---------------- repack: vh[b][c][j] -> B-frag-ready vswz ----------------
// vswz element index = (((b*128 + j/32)*64 + c)*4 + (j%32)/8)*8 + j%8
// => attn instruction (nb,kb): lane(quad,m16) reads 16B at
//    ((( (j0/32)+kb )*64 + nb*16+m16)*4 + quad)*16B  -> wave covers 1KB contiguous
__global__ __launch_bounds__(256) void repack_kernel(
    const _Float16* __restrict__ vh, _Float16* __restrict__ vswz)
{
    __shared__ _Float16 vt[CDIM][VTP];

    const int b   = blockIdx.x >> 6;       // 4 b * 64 jblk
    const int jb64= blockIdx.x & 63;
    const int j0  = jb64 * 64;
    const int tid = threadIdx.x;

    // phase A: coalesced-ish read of V rows into LDS tile [c][j-local]
    {
        const int c   = tid >> 2;
        const int seg = tid & 3;
        const _Float16* src = vh + ((size_t)(b * CDIM + c)) * NPOS + j0 + seg * 16;
        const f16x8 a0 = *(const f16x8*)src;
        const f16x8 a1 = *(const f16x8*)(src + 8);
        *(f16x8*)&vt[c][seg * 16]     = a0;
        *(f16x8*)&vt[c][seg * 16 + 8] = a1;
    }
    __syncthreads();

    // phase B: emit 16B granules, contiguous global stores
    _Float16* dstb = vswz + ((size_t)(b * 128 + jb64 * 2)) * 64 * 32;
#pragma unroll
    for (int gi = 0; gi < 2; ++gi) {
        const int g    = tid * 2 + gi;     // 0..511
        const int jsub = g & 3;
        const int c    = (g >> 2) & 63;
        const int jsL  = (g >> 8) & 1;
        const f16x8 val = *(const f16x8*)&vt[c][jsL * 32 + jsub * 8];
        *(f16x8*)(dstb + (size_t)g * 8) = val;
    }
}

// ---------------- flash attention: two-pass, coalesced V ----------------
__global__ __launch_bounds__(256, 4) void attn_kernel(
    const _Float16* __restrict__ qh, const _Float16* __restrict__ kh,
    const _Float16* __restrict__ vswz,
    _Float16* __restrict__ po, float* __restrict__ pm, float* __restrict__ pl)
{
    __shared__ _Float16 pt[4][16][PTP];   // per-wave private P-transform tile

    const int bid   = blockIdx.x;
    const int split = bid & (SPLIT - 1);
    const int itile = (bid >> 2) & 63;
    const int b     = bid >> 8;
    const int tid   = threadIdx.x;
    const int wave  = tid >> 6;
    const int lane  = tid & 63;
    const int quad  = lane >> 4;
    const int m16   = lane & 15;

    const int i0 = itile * 64 + wave * 16;

    // Q A-fragment: A[m=m16][k=quad*8+u]; zero k>=8 (quads 1..3)
    f16x8 qa = *(const f16x8*)(qh + ((size_t)(b * NPOS + i0 + m16)) * CKD);
    if (quad != 0) qa = (f16x8){};

    const _Float16* kchunk = kh + ((size_t)(b * NPOS + split * JCHUNK)) * CKD;
    // granule base for this b; per-lane fixed part of the V address
    const _Float16* vg = vswz + ((size_t)b * 128) * 64 * 32;

    // ---- pass 1: chunk row max ----
    float mloc[4];
#pragma unroll
    for (int r = 0; r < 4; ++r) mloc[r] = -1e30f;

    for (int it = 0; it < NITER; ++it) {
        const int j0 = it * 64;
        f16x8 kf[4];
#pragma unroll
        for (int jb = 0; jb < 4; ++jb)
            kf[jb] = *(const f16x8*)(kchunk + (size_t)(j0 + jb * 16 + m16) * CKD);
#pragma unroll
        for (int jb = 0; jb < 4; ++jb) {
            const f32x4 s = __builtin_amdgcn_mfma_f32_16x16x32_f16(
                qa, kf[jb], (f32x4){0.f, 0.f, 0.f, 0.f}, 0, 0, 0);
#pragma unroll
            for (int r = 0; r < 4; ++r) mloc[r] = fmaxf(mloc[r], s[r]);
        }
    }
#pragma unroll
    for (int d = 1; d < 16; d <<= 1)
#pragma unroll
        for (int r = 0; r < 4; ++r)
            mloc[r] = fmaxf(mloc[r], __shfl_xor(mloc[r], d));

    // ---- pass 2: exp -> P -> PV MFMA; l via ones-column MFMA ----
    f32x4 acc[4], accl;
#pragma unroll
    for (int nb = 0; nb < 4; ++nb) acc[nb] = (f32x4){0.f, 0.f, 0.f, 0.f};
    accl = (f32x4){0.f, 0.f, 0.f, 0.f};
    const f16x8 vones = {(_Float16)1.f, (_Float16)1.f, (_Float16)1.f, (_Float16)1.f,
                         (_Float16)1.f, (_Float16)1.f, (_Float16)1.f, (_Float16)1.f};

    for (int it = 0; it < NITER; ++it) {
        const int j0     = it * 64;
        const int jsuper = split * 32 + it * 2;

        // V B-frags, coalesced granule loads (1KB contiguous per instruction)
        f16x8 va[4], vb[4];
#pragma unroll
        for (int nb = 0; nb < 4; ++nb) {
            const size_t g0 = ((size_t)(jsuper      ) * 64 + nb * 16 + m16) * 4 + quad;
            const size_t g1 = ((size_t)(jsuper + 1  ) * 64 + nb * 16 + m16) * 4 + quad;
            va[nb] = *(const f16x8*)(vg + g0 * 8);
            vb[nb] = *(const f16x8*)(vg + g1 * 8);
        }

        // S = Q K^T
        f32x4 sf[4];
#pragma unroll
        for (int jb = 0; jb < 4; ++jb) {
            const f16x8 kf = *(const f16x8*)(kchunk + (size_t)(j0 + jb * 16 + m16) * CKD);
            sf[jb] = __builtin_amdgcn_mfma_f32_16x16x32_f16(
                qa, kf, (f32x4){0.f, 0.f, 0.f, 0.f}, 0, 0, 0);
        }

        // P = exp(S - m), straight to LDS in A-layout (m is lane-local)
#pragma unroll
        for (int jb = 0; jb < 4; ++jb)
#pragma unroll
            for (int r = 0; r < 4; ++r)
                pt[wave][quad * 4 + r][jb * 16 + m16] = (_Float16)__expf(sf[jb][r] - mloc[r]);

        const f16x8 pa0 = *(const f16x8*)&pt[wave][m16][quad * 8];
        const f16x8 pa1 = *(const f16x8*)&pt[wave][m16][32 + quad * 8];

        accl = __builtin_amdgcn_mfma_f32_16x16x32_f16(pa0, vones, accl, 0, 0, 0);
#pragma unroll
        for (int nb = 0; nb < 4; ++nb)
            acc[nb] = __builtin_amdgcn_mfma_f32_16x16x32_f16(pa0, va[nb], acc[nb], 0, 0, 0);
        accl = __builtin_amdgcn_mfma_f32_16x16x32_f16(pa1, vones, accl, 0, 0, 0);
#pragma unroll
        for (int nb = 0; nb < 4; ++nb)
            acc[nb] = __builtin_amdgcn_mfma_f32_16x16x32_f16(pa1, vb[nb], acc[nb], 0, 0, 0);
    }

    // ---- epilogue ----
    const int sb = split * BATCH + b;
    if (m16 == 0) {
#pragma unroll
        for (int r = 0; r < 4; ++r) {
            const int i = i0 + quad * 4 + r;
            pm[(size_t)sb * NPOS + i] = mloc[r];
            pl[(size_t)sb * NPOS + i] = accl[r];
        }
    }
#pragma unroll
    for (int nb = 0; nb < 4; ++nb)
#pragma unroll
        for (int r = 0; r < 4; ++r)
            pt[wave][quad * 4 + r][nb * 16 + m16] = (_Float16)acc[nb][r];
#pragma unroll
    for (int g = 0; g < 16; ++g) {
        const int c = quad + g * 4;
        po[((size_t)sb * CDIM + c) * NPOS + i0 + m16] = pt[wave][m16][c];
    }
}

// ---------------- combine split-j partials + gamma*O + x ----------------
__global__ __launch_bounds__(256) void combine_kernel(
    const float* __restrict__ x,
    const _Float16* __restrict__ po, const float* __restrict__ pm,
    const float* __restrict__ pl,
    const float* __restrict__ gamma, float* __restrict__ out)
{
    const int t = blockIdx.x * 256 + threadIdx.x;   // 1,048,576 threads
    const int b = t >> 18;
    const int c = (t >> 12) & 63;
    const int i = t & 4095;

    float m[SPLIT], l[SPLIT];
#pragma unroll
    for (int s = 0; s < SPLIT; ++s) {
        m[s] = pm[((size_t)(s * BATCH + b)) * NPOS + i];
        l[s] = pl[((size_t)(s * BATCH + b)) * NPOS + i];
    }
    float ms = m[0];
#pragma unroll
    for (int s = 1; s < SPLIT; ++s) ms = fmaxf(ms, m[s]);

    float L = 0.f, O = 0.f;
#pragma unroll
    for (int s = 0; s < SPLIT; ++s) {
        const float w = __expf(m[s] - ms);
        L += l[s] * w;
        O = fmaf(w, (float)po[(((size_t)(s * BATCH + b)) * CDIM + c) * NPOS + i], O);
    }
    const size_t xi = ((size_t)(b * CDIM + c)) * NPOS + i;
    out[xi] = fmaf(gamma[0], O / L, x[xi]);
}

// ---------------- launch ----------------
extern "C" void kernel_launch(void* const* d_in, const int* in_sizes, int n_in,
                              void* d_out, int out_size, void* d_ws, size_t ws_size,
                              hipStream_t stream)
{
    const float* x     = (const float*)d_in[0];
    const float* wq    = (const float*)d_in[1];
    const float* bq    = (const float*)d_in[2];
    const float* wk    = (const float*)d_in[3];
    const float* bk    = (const float*)d_in[4];
    const float* wv    = (const float*)d_in[5];
    const float* bv    = (const float*)d_in[6];
    const float* gamma = (const float*)d_in[7];
    float* out = (float*)d_out;

    // layout (po aliases vh, which is dead after repack):
    // [0,256K) qh | [256K,512K) kh | [512K,2.5M) vswz | [2.5M,4.5M) vh | [2.5M,10.5M) po
    // [10.5M,10.75M) pm | [10.75M,11M) pl
    char* ws = (char*)d_ws;
    _Float16* qh   = (_Float16*)(ws);
    _Float16* kh   = (_Float16*)(ws + (256 << 10));
    _Float16* vswz = (_Float16*)(ws + (512 << 10));
    _Float16* vh   = (_Float16*)(ws + (2560 << 10));
    _Float16* po   = (_Float16*)(ws + (2560 << 10));   // alias over vh (8 MB)
    float*    pm   = (float*)   (ws + (10752 << 10));
    float*    pl   = (float*)   (ws + (11008 << 10));

    proj_kernel<<<256, 256, 0, stream>>>(x, wq, bq, wk, bk, wv, bv, qh, kh, vh);
    repack_kernel<<<BATCH * 64, 256, 0, stream>>>(vh, vswz);
    attn_kernel<<<BATCH * 64 * SPLIT, 256, 0, stream>>>(qh, kh, vswz, po, pm, pl);
    combine_kernel<<<4096, 256, 0, stream>>>(x, po, pm, pl, gamma, out);
}